// Round 7
// baseline (7209.536 us; speedup 1.0000x reference)
//
#include <hip/hip_runtime.h>
#include <cstddef>

// Problem constants
#define B_TOT 4096
#define T_LEN 168
#define D_IN  16
#define H_DIM 96

#define NTHR 768   // 12 waves; tid = u*8 + kq (u 0..95, kq 0..7)
#define HP   104   // layer-0 padded h row (bank-verified; conflicts ~0 measured)
#define VP   196   // layer-1 combined [x|h] row (bank-verified; conflicts 0 measured)

__device__ __forceinline__ float sigm(float x) {
  return __fdividef(1.f, 1.f + __expf(-x));
}
__device__ __forceinline__ float tanh_fast(float x) {
  float ax = fabsf(x);
  float z  = __expf(-2.f * ax);
  return copysignf(__fdividef(1.f - z, 1.f + z), x);
}

// DPP cross-lane move (VALU pipe — keeps the reduction off the DS pipe).
// CTRL: 0xB1 = quad_perm [1,0,3,2] (xor-1), 0x4E = quad_perm [2,3,0,1] (xor-2),
//       0x141 = row_half_mirror (xor-7 within octet).
template<int CTRL>
__device__ __forceinline__ float dppmov(float x) {
  return __builtin_bit_cast(float,
      __builtin_amdgcn_update_dpp(0, __builtin_bit_cast(int, x),
                                  CTRL, 0xF, 0xF, true));
}

// Retiring DPP butterfly: slot i of lane l holds batch l^i partial; after the
// three rounds slot0 = full K-sum for batch l.  (Round m pairs slot i with i^m
// from lane l^m: batch (l^m)^(i^m) = l^i, so batches stay aligned.)
#define BUTTERFLY(accj)                         \
  do {                                          \
    accj[0] += dppmov<0x141>(accj[7]);          \
    accj[1] += dppmov<0x141>(accj[6]);          \
    accj[2] += dppmov<0x141>(accj[5]);          \
    accj[3] += dppmov<0x141>(accj[4]);          \
    accj[0] += dppmov<0x4E>(accj[2]);           \
    accj[1] += dppmov<0x4E>(accj[3]);           \
    accj[0] += dppmov<0xB1>(accj[1]);           \
  } while (0)

// ---------------- Layer 0 ----------------
// One 8-batch tile per block; grid 512 -> 2 blocks/CU (24 waves) for barrier
// overlap.  x read directly from global (L2/L3-hot, 8 tiny loads/thread/step)
// so LDS shrinks to the 6.6 KB h double-buffer.
__global__ __launch_bounds__(NTHR, 6)
void lstm0_kernel(const float* __restrict__ in,    // (B,T,16)
                  const float* __restrict__ wih,   // (384,16)
                  const float* __restrict__ whh,   // (384,96)
                  const float* __restrict__ bih,
                  const float* __restrict__ bhh,
                  float* __restrict__ h_out)       // (B,T,96)
{
  __shared__ float h_s[2][8][HP];

  const int tid = threadIdx.x;
  const int u   = tid >> 3;
  const int kq  = tid & 7;
  const int gb0 = blockIdx.x * 8;

  float4 wB[4][3];   // Whh rows u+96j, k-slice [12kq,12kq+12)
  #pragma unroll
  for (int j = 0; j < 4; ++j)
    #pragma unroll
    for (int c = 0; c < 3; ++c)
      wB[j][c] = *(const float4*)(whh + (size_t)(u + 96 * j) * 96 + kq * 12 + 4 * c);

  float2 wA0[4];     // Wih rows u+96j, k-slice [2kq,2kq+2)
  #pragma unroll
  for (int j = 0; j < 4; ++j)
    wA0[j] = *(const float2*)(wih + (u + 96 * j) * D_IN + kq * 2);

  float bias[4];
  #pragma unroll
  for (int j = 0; j < 4; ++j) bias[j] = bih[u + 96 * j] + bhh[u + 96 * j];

  for (int idx = tid; idx < 8 * HP; idx += NTHR) (&h_s[0][0][0])[idx] = 0.f;
  __syncthreads();

  float cst = 0.f;

  #pragma unroll 1
  for (int t = 0; t < T_LEN; ++t) {
    const int rd = t & 1;
    const float* hr = &h_s[rd][0][0];
    float*       hw = &h_s[rd ^ 1][0][0];

    // issue x loads early (slot i -> batch kq^i); L2/L3-hot
    float2 xv2[8];
    #pragma unroll
    for (int i = 0; i < 8; ++i)
      xv2[i] = *(const float2*)(in + ((size_t)(gb0 + (kq ^ i)) * T_LEN + t) * D_IN + kq * 2);

    float acc[4][8];
    #pragma unroll
    for (int j = 0; j < 4; ++j)
      #pragma unroll
      for (int i = 0; i < 8; ++i) acc[j][i] = 0.f;

    // B-part: h @ Whh^T from LDS (bank-verified)
    #pragma unroll
    for (int c = 0; c < 3; ++c) {
      float4 hv[8];
      #pragma unroll
      for (int i = 0; i < 8; ++i)
        hv[i] = *(const float4*)&hr[(kq ^ i) * HP + kq * 12 + 4 * c];
      #pragma unroll
      for (int j = 0; j < 4; ++j)
        #pragma unroll
        for (int i = 0; i < 8; ++i)
          acc[j][i] = fmaf(wB[j][c].x, hv[i].x, fmaf(wB[j][c].y, hv[i].y,
                      fmaf(wB[j][c].z, hv[i].z, fmaf(wB[j][c].w, hv[i].w, acc[j][i]))));
    }

    // A-part: x @ Wih^T
    #pragma unroll
    for (int j = 0; j < 4; ++j)
      #pragma unroll
      for (int i = 0; i < 8; ++i)
        acc[j][i] = fmaf(wA0[j].x, xv2[i].x, fmaf(wA0[j].y, xv2[i].y, acc[j][i]));

    #pragma unroll
    for (int j = 0; j < 4; ++j) BUTTERFLY(acc[j]);

    const float gi = acc[0][0] + bias[0];
    const float gf = acc[1][0] + bias[1];
    const float gg = acc[2][0] + bias[2];
    const float go = acc[3][0] + bias[3];
    cst = sigm(gf) * cst + sigm(gi) * tanh_fast(gg);
    const float hn = sigm(go) * tanh_fast(cst);
    hw[kq * HP + u] = hn;
    h_out[((size_t)(gb0 + kq) * T_LEN + t) * H_DIM + u] = hn;

    __syncthreads();
  }
}

// ---------------- Layer 1 ----------------
// Combined-K GEMM over concat[x_t; h_t] (K=192); one 8-batch tile per block,
// grid 512 -> 2 blocks/CU.  Per-step vector double-buffered in 12.5 KB LDS.
__global__ __launch_bounds__(NTHR, 6)
void lstm1_kernel(const float* __restrict__ in,    // (B,T,96) = h1
                  const float* __restrict__ wih,   // (384,96)
                  const float* __restrict__ whh,   // (384,96)
                  const float* __restrict__ bih,
                  const float* __restrict__ bhh,
                  const float* __restrict__ wfc,   // (96)
                  const float* __restrict__ bfc,   // (1)
                  float* __restrict__ out)         // (B,)
{
  __shared__ float cb[2][8][VP];   // [0..96)=x_t, [96..192)=h_t

  const int tid = threadIdx.x;
  const int u   = tid >> 3;
  const int kq  = tid & 7;
  const int gb0 = blockIdx.x * 8;

  // combined weight slice: rows u+96j, k in [24kq, 24kq+24) of [Wih|Whh]
  float4 w[4][6];
  #pragma unroll
  for (int j = 0; j < 4; ++j) {
    const size_t row = (size_t)(u + 96 * j) * 96;
    const float* wsrc = (kq < 4) ? (wih + row + kq * 24) : (whh + row + (kq - 4) * 24);
    #pragma unroll
    for (int c = 0; c < 6; ++c) w[j][c] = *(const float4*)(wsrc + 4 * c);
  }

  float bias[4];
  #pragma unroll
  for (int j = 0; j < 4; ++j) bias[j] = bih[u + 96 * j] + bhh[u + 96 * j];

  const int xb = tid / 96;          // x-staging: batch row 0..7
  const int xc = tid - xb * 96;     //            col 0..95
  const float* xin = in + (size_t)(gb0 + xb) * T_LEN * 96 + xc;

  cb[0][kq][96 + u] = 0.f;          // h0 = 0 (768 writes cover 8x96 exactly)
  cb[0][xb][xc]     = xin[0];       // x_0
  __syncthreads();

  float cst = 0.f;

  #pragma unroll 1
  for (int t = 0; t < T_LEN; ++t) {
    const int rd = t & 1;
    const float* v  = &cb[rd][0][0];
    float*       vw = &cb[rd ^ 1][0][0];

    float xstage = 0.f;
    if (t + 1 < T_LEN) xstage = xin[(size_t)(t + 1) * 96];   // issue early

    float acc[4][8];
    #pragma unroll
    for (int j = 0; j < 4; ++j)
      #pragma unroll
      for (int i = 0; i < 8; ++i) acc[j][i] = 0.f;

    // K=192 in 6 float4 chunks; hv in two groups of 4 to cap liveness
    #pragma unroll
    for (int c = 0; c < 6; ++c) {
      {
        float4 hv[4];
        #pragma unroll
        for (int i = 0; i < 4; ++i)
          hv[i] = *(const float4*)&v[(kq ^ i) * VP + kq * 24 + 4 * c];
        #pragma unroll
        for (int j = 0; j < 4; ++j)
          #pragma unroll
          for (int i = 0; i < 4; ++i)
            acc[j][i] = fmaf(w[j][c].x, hv[i].x, fmaf(w[j][c].y, hv[i].y,
                        fmaf(w[j][c].z, hv[i].z, fmaf(w[j][c].w, hv[i].w, acc[j][i]))));
      }
      {
        float4 hv[4];
        #pragma unroll
        for (int i = 0; i < 4; ++i)
          hv[i] = *(const float4*)&v[(kq ^ (i + 4)) * VP + kq * 24 + 4 * c];
        #pragma unroll
        for (int j = 0; j < 4; ++j)
          #pragma unroll
          for (int i = 0; i < 4; ++i)
            acc[j][i + 4] = fmaf(w[j][c].x, hv[i].x, fmaf(w[j][c].y, hv[i].y,
                            fmaf(w[j][c].z, hv[i].z, fmaf(w[j][c].w, hv[i].w, acc[j][i + 4]))));
      }
    }

    #pragma unroll
    for (int j = 0; j < 4; ++j) BUTTERFLY(acc[j]);

    const float gi = acc[0][0] + bias[0];
    const float gf = acc[1][0] + bias[1];
    const float gg = acc[2][0] + bias[2];
    const float go = acc[3][0] + bias[3];
    cst = sigm(gf) * cst + sigm(gi) * tanh_fast(gg);
    const float hn = sigm(go) * tanh_fast(cst);

    vw[kq * VP + 96 + u] = hn;                      // h_{t+1}
    if (t + 1 < T_LEN) vw[xb * VP + xc] = xstage;   // x_{t+1} (write late)

    __syncthreads();
  }

  // fused FC on last h (in cb[0]: T=168 even)
  if (tid < 8) {
    float s = bfc[0];
    const float* hl = &cb[0][tid][96];
    #pragma unroll 4
    for (int uu = 0; uu < H_DIM; ++uu) s = fmaf(hl[uu], wfc[uu], s);
    out[gb0 + tid] = s;
  }
}

extern "C" void kernel_launch(void* const* d_in, const int* in_sizes, int n_in,
                              void* d_out, int out_size, void* d_ws, size_t ws_size,
                              hipStream_t stream) {
  (void)in_sizes; (void)n_in; (void)out_size; (void)ws_size;

  const float* x    = (const float*)d_in[0];
  const float* Wih0 = (const float*)d_in[1];
  const float* Whh0 = (const float*)d_in[2];
  const float* bih0 = (const float*)d_in[3];
  const float* bhh0 = (const float*)d_in[4];
  const float* Wih1 = (const float*)d_in[5];
  const float* Whh1 = (const float*)d_in[6];
  const float* bih1 = (const float*)d_in[7];
  const float* bhh1 = (const float*)d_in[8];
  const float* Wfc  = (const float*)d_in[9];
  const float* bfc  = (const float*)d_in[10];
  float* out = (float*)d_out;

  float* h1 = (float*)d_ws;   // (B,T,96) fp32

  dim3 grid(B_TOT / 8);   // 512 blocks of one 8-batch tile -> 2 blocks/CU
  dim3 block(NTHR);

  lstm0_kernel<<<grid, block, 0, stream>>>(x, Wih0, Whh0, bih0, bhh0, h1);
  lstm1_kernel<<<grid, block, 0, stream>>>(h1, Wih1, Whh1, bih1, bhh1, Wfc, bfc, out);
}

// Round 8
// 1055.686 us; speedup vs baseline: 6.8292x; 6.8292x over previous
//
#include <hip/hip_runtime.h>
#include <cstddef>

// Problem constants
#define B_TOT 4096
#define T_LEN 168
#define NTHR  512   // 8 waves: 6 c-waves (i,f,g x 16 units each) + 2 o-waves (3 o-tiles each)

typedef __attribute__((ext_vector_type(8))) short  short8;   // bf16x8 MFMA frag (guide §3)
typedef __attribute__((ext_vector_type(4))) short  short4v;
typedef __attribute__((ext_vector_type(4))) float  f32x4;

__device__ __forceinline__ short f2bf(float f) {   // RTNE fp32 -> bf16 bits
  unsigned u = __builtin_bit_cast(unsigned, f);
  return (short)((u + 0x7fffu + ((u >> 16) & 1u)) >> 16);
}
__device__ __forceinline__ float bf2f(short b) {
  return __builtin_bit_cast(float, ((unsigned)(unsigned short)b) << 16);
}
__device__ __forceinline__ float sigm(float x) {
  return __fdividef(1.f, 1.f + __expf(-x));
}
__device__ __forceinline__ float tanh_fast(float x) {
  float ax = fabsf(x);
  float z  = __expf(-2.f * ax);
  return copysignf(__fdividef(1.f - z, 1.f + z), x);
}

// One LSTM layer on MFMA. Per block: 16 batches (M=16 tile), all 168 steps.
// v_t = concat[x_t ; h_t] (K = XS+96, padded to 32*KF).  Weights as 16x16x32
// B-frags, bf16 + bf16-residual, register-resident (3 tiles x KF x 2 = 96|144 VGPR).
// Split product: Ab*Wb + Ar*Wb + Ab*Wr  => error ~2^-18 (fp32-grade).
// A-frag layout (AMD lab-notes, C/D m89-verified): A: lane m=l&15, k=8*(l>>4)+e;
// B: lane n=l&15 (gate), k=8*(l>>4)+e; D: n=l&15, m=4*(l>>4)+reg.
// c-waves (wv 0..5): tiles {i,f,g} of units [16wv,16wv+16) -> i/f/g lane-local,
// c-state in regs, write tanh(c) to LDS.  o-waves (wv 6,7): 3 o-tiles each,
// read tanh(c), produce h, write next A-frags (and h_out for layer 0).
template<int XS, int KF, int PAD, bool L0>
__global__ __launch_bounds__(NTHR, 2)
void lstm_mfma(const float* __restrict__ in,     // L0: x (B,T,16); L1: h1 (B,T,96)
               const float* __restrict__ wih,    // (384,XS)
               const float* __restrict__ whh,    // (384,96)
               const float* __restrict__ bih,
               const float* __restrict__ bhh,
               float* __restrict__ h_out,        // L0: h1 out (B,T,96)
               const float* __restrict__ wfc,    // L1
               const float* __restrict__ bfc,    // L1
               float* __restrict__ out)          // L1: (B,)
{
  static_assert((PAD * 2) % 16 == 0, "row alignment");
  __shared__ __align__(16) short vb[2][16][PAD];   // v_t bf16   (double-buffered)
  __shared__ __align__(16) short vr[2][16][PAD];   // v_t residual
  __shared__ float tc_s[16][100];                  // tanh(c) [b][u] (+FC scratch)

  const int tid  = threadIdx.x;
  const int lane = tid & 63;
  const int wv   = tid >> 6;        // 0..7
  const bool cw  = (wv < 6);
  const int lr   = lane & 15;
  const int lk   = lane >> 4;
  const int gb0  = blockIdx.x * 16;

  // ---- weight fragments: bf16 + residual (once) ----
  short8 wb[3][KF], wr[3][KF];
  #pragma unroll
  for (int tt = 0; tt < 3; ++tt) {
    const int gbase = cw ? (96 * tt + 16 * wv) : (288 + 16 * (3 * (wv - 6) + tt));
    const int row = gbase + lr;
    #pragma unroll
    for (int kf = 0; kf < KF; ++kf)
      #pragma unroll
      for (int e = 0; e < 8; ++e) {
        const int k = 32 * kf + 8 * lk + e;
        float f = 0.f;
        if (k < XS)          f = wih[row * XS + k];
        else if (k < XS + 96) f = whh[row * 96 + (k - XS)];
        const short hi = f2bf(f);
        wb[tt][kf][e] = hi;
        wr[tt][kf][e] = f2bf(f - bf2f(hi));
      }
  }

  // biases (per-lane gate columns)
  float bI = 0.f, bF = 0.f, bG = 0.f, bO[3] = {0.f, 0.f, 0.f};
  if (cw) {
    const int u = 16 * wv + lr;
    bI = bih[u] + bhh[u];
    bF = bih[96 + u] + bhh[96 + u];
    bG = bih[192 + u] + bhh[192 + u];
  } else {
    #pragma unroll
    for (int a = 0; a < 3; ++a) {
      const int g = 288 + 16 * (3 * (wv - 6) + a) + lr;
      bO[a] = bih[g] + bhh[g];
    }
  }

  // ---- init: zero v buffers (h0 = 0 + zero K-pad), stage x_0 ----
  for (int idx = tid; idx < 2 * 16 * PAD; idx += NTHR) {
    (&vb[0][0][0])[idx] = 0;
    (&vr[0][0][0])[idx] = 0;
  }
  __syncthreads();
  if constexpr (L0) {
    if (tid < 256) {
      const int b = tid >> 4, d = tid & 15;
      const float xv = in[((size_t)(gb0 + b) * T_LEN + 0) * XS + d];
      const short p = f2bf(xv);
      vb[0][b][d] = p;
      vr[0][b][d] = f2bf(xv - bf2f(p));
    }
  } else {
    if (tid < 384) {
      const int b = tid / 24, u4 = tid % 24;
      const float4 xv = *(const float4*)&in[((size_t)(gb0 + b) * T_LEN + 0) * 96 + 4 * u4];
      short4v pb, pr;
      pb[0]=f2bf(xv.x); pr[0]=f2bf(xv.x - bf2f(pb[0]));
      pb[1]=f2bf(xv.y); pr[1]=f2bf(xv.y - bf2f(pb[1]));
      pb[2]=f2bf(xv.z); pr[2]=f2bf(xv.z - bf2f(pb[2]));
      pb[3]=f2bf(xv.w); pr[3]=f2bf(xv.w - bf2f(pb[3]));
      *(short4v*)&vb[0][b][4 * u4] = pb;
      *(short4v*)&vr[0][b][4 * u4] = pr;
    }
  }
  __syncthreads();

  float cst[4] = {0.f, 0.f, 0.f, 0.f};
  float hlast[3][4];
  #pragma unroll
  for (int a = 0; a < 3; ++a)
    #pragma unroll
    for (int r = 0; r < 4; ++r) hlast[a][r] = 0.f;

  #pragma unroll 1
  for (int t = 0; t < T_LEN; ++t) {
    const int cur = t & 1, nxt = cur ^ 1;
    const bool hasnext = (t + 1 < T_LEN);

    // early-issue x_{t+1} global load (hides under MFMA phase)
    float  xs1 = 0.f;
    float4 xs4 = {0.f, 0.f, 0.f, 0.f};
    if constexpr (L0) {
      if (tid < 256 && hasnext)
        xs1 = in[((size_t)(gb0 + (tid >> 4)) * T_LEN + (t + 1)) * XS + (tid & 15)];
    } else {
      if (tid < 384 && hasnext)
        xs4 = *(const float4*)&in[((size_t)(gb0 + tid / 24) * T_LEN + (t + 1)) * 96 + 4 * (tid % 24)];
    }

    // A-frags (2-way banks max: PAD*2 mod 128 = 16|80 spreads rows)
    short8 ab[KF], ar[KF];
    #pragma unroll
    for (int kf = 0; kf < KF; ++kf) {
      const int off = lr * PAD + kf * 32 + lk * 8;
      ab[kf] = *(const short8*)&(&vb[cur][0][0])[off];
      ar[kf] = *(const short8*)&(&vr[cur][0][0])[off];
    }

    f32x4 acc[3] = {};
    #pragma unroll
    for (int tt = 0; tt < 3; ++tt)
      #pragma unroll
      for (int kf = 0; kf < KF; ++kf) {
        acc[tt] = __builtin_amdgcn_mfma_f32_16x16x32_bf16(ab[kf], wb[tt][kf], acc[tt], 0, 0, 0);
        acc[tt] = __builtin_amdgcn_mfma_f32_16x16x32_bf16(ar[kf], wb[tt][kf], acc[tt], 0, 0, 0);
        acc[tt] = __builtin_amdgcn_mfma_f32_16x16x32_bf16(ab[kf], wr[tt][kf], acc[tt], 0, 0, 0);
      }

    if (cw) {
      // i/f/g lane-local: batch m = 4*lk+r, unit u = 16*wv+lr
      #pragma unroll
      for (int r = 0; r < 4; ++r) {
        const float gi = sigm(acc[0][r] + bI);
        const float gf = sigm(acc[1][r] + bF);
        const float gg = tanh_fast(acc[2][r] + bG);
        cst[r] = gf * cst[r] + gi * gg;
        tc_s[4 * lk + r][16 * wv + lr] = tanh_fast(cst[r]);
      }
      // write x_{t+1} into next buffer (c-waves; o-waves write h after B2)
      if constexpr (L0) {
        if (tid < 256 && hasnext) {
          const short p = f2bf(xs1);
          vb[nxt][tid >> 4][tid & 15] = p;
          vr[nxt][tid >> 4][tid & 15] = f2bf(xs1 - bf2f(p));
        }
      } else {
        if (tid < 384 && hasnext) {
          short4v pb, pr;
          pb[0]=f2bf(xs4.x); pr[0]=f2bf(xs4.x - bf2f(pb[0]));
          pb[1]=f2bf(xs4.y); pr[1]=f2bf(xs4.y - bf2f(pb[1]));
          pb[2]=f2bf(xs4.z); pr[2]=f2bf(xs4.z - bf2f(pb[2]));
          pb[3]=f2bf(xs4.w); pr[3]=f2bf(xs4.w - bf2f(pb[3]));
          *(short4v*)&vb[nxt][tid / 24][4 * (tid % 24)] = pb;
          *(short4v*)&vr[nxt][tid / 24][4 * (tid % 24)] = pr;
        }
      }
    }
    __syncthreads();   // B2: tanh(c) visible to o-waves
    if (!cw) {
      const int ow = wv - 6;
      #pragma unroll
      for (int a = 0; a < 3; ++a) {
        const int uu = 16 * (3 * ow + a) + lr;
        #pragma unroll
        for (int r = 0; r < 4; ++r) {
          const float o  = sigm(acc[a][r] + bO[a]);
          const float h  = o * tc_s[4 * lk + r][uu];
          const short hb = f2bf(h);
          vb[nxt][4 * lk + r][XS + uu] = hb;
          vr[nxt][4 * lk + r][XS + uu] = f2bf(h - bf2f(hb));
          if constexpr (L0)
            h_out[((size_t)(gb0 + 4 * lk + r) * T_LEN + t) * 96 + uu] = h;
          else
            hlast[a][r] = h;
        }
      }
    }
    __syncthreads();   // B3: next A-frags ready
  }

  if constexpr (!L0) {
    // fused FC: out[b] = h_T[b] . wfc + bfc  (h_T fp32 in o-wave regs)
    if (!cw) {
      const int ow = wv - 6;
      #pragma unroll
      for (int r = 0; r < 4; ++r) {
        float p = 0.f;
        #pragma unroll
        for (int a = 0; a < 3; ++a)
          p += hlast[a][r] * wfc[16 * (3 * ow + a) + lr];
        tc_s[4 * lk + r][lr + 16 * ow] = p;   // 32 partials per batch row
      }
    }
    __syncthreads();
    if (tid < 16) {
      float s = bfc[0];
      #pragma unroll 4
      for (int j = 0; j < 32; ++j) s += tc_s[tid][j];
      out[gb0 + tid] = s;
    }
  }
}

extern "C" void kernel_launch(void* const* d_in, const int* in_sizes, int n_in,
                              void* d_out, int out_size, void* d_ws, size_t ws_size,
                              hipStream_t stream) {
  (void)in_sizes; (void)n_in; (void)out_size; (void)ws_size;

  const float* x    = (const float*)d_in[0];
  const float* Wih0 = (const float*)d_in[1];
  const float* Whh0 = (const float*)d_in[2];
  const float* bih0 = (const float*)d_in[3];
  const float* bhh0 = (const float*)d_in[4];
  const float* Wih1 = (const float*)d_in[5];
  const float* Whh1 = (const float*)d_in[6];
  const float* bih1 = (const float*)d_in[7];
  const float* bhh1 = (const float*)d_in[8];
  const float* Wfc  = (const float*)d_in[9];
  const float* bfc  = (const float*)d_in[10];
  float* out = (float*)d_out;

  float* h1 = (float*)d_ws;   // (B,T,96) fp32 = 252 MiB

  dim3 grid(B_TOT / 16);      // 256 blocks, 16 batches each (M=16 MFMA tile)
  dim3 block(NTHR);

  // layer0: K = 16+96 = 112 -> KF=4 (pad 128), row pad 136 shorts
  lstm_mfma<16, 4, 136, true><<<grid, block, 0, stream>>>(
      x, Wih0, Whh0, bih0, bhh0, h1, nullptr, nullptr, nullptr);
  // layer1: K = 96+96 = 192 -> KF=6, row pad 200 shorts
  lstm_mfma<96, 6, 200, false><<<grid, block, 0, stream>>>(
      h1, Wih1, Whh1, bih1, bhh1, nullptr, Wfc, bfc, out);
}